// Round 16
// baseline (47.563 us; speedup 1.0000x reference)
//
#include <hip/hip_runtime.h>
#include <math.h>

#define ATOMS 200
#define FPT 16   // frames per thread (amortizes index math, provides ILP)
#define G   4    // frames per unrolled group (independent chains in flight)
#define REP 3    // DIAGNOSTIC: replicate identical work so the dispatch
                 // outranks the harness memsets in the duration-sorted
                 // profile table and we finally see this kernel's counters.
                 // All z-slices write identical values (deterministic).

static __device__ __forceinline__ float3 f3(float x, float y, float z) {
    return make_float3(x, y, z);
}
static __device__ __forceinline__ float3 sub3(float3 a, float3 b) {
    return f3(a.x - b.x, a.y - b.y, a.z - b.z);
}
static __device__ __forceinline__ float dot3(float3 a, float3 b) {
    return fmaf(a.x, b.x, fmaf(a.y, b.y, a.z * b.z));
}
static __device__ __forceinline__ float3 cross3(float3 a, float3 b) {
    return f3(fmaf(a.y, b.z, -a.z * b.y),
              fmaf(a.z, b.x, -a.x * b.z),
              fmaf(a.x, b.y, -a.y * b.x));
}

// two consecutive atoms (24B) in one packed access
struct __attribute__((packed, aligned(4))) f6 { float v[6]; };

// asin via A&S 4.4.45: abs err <= 6.8e-5 rad (threshold is 2e-2)
static __device__ __forceinline__ float asin_fast(float x) {
    float a = fminf(fabsf(x), 1.0f);
    float t = __builtin_amdgcn_sqrtf(1.0f - a);
    float p = fmaf(a, -0.0187293f, 0.0742610f);
    p = fmaf(a, p, -0.2121144f);
    p = fmaf(a, p, 1.5707288f);
    return copysignf(fmaf(-t, p, 1.5707963267948966f), x);
}

static __device__ __forceinline__ float writhe_elem(const f6& A, const f6& B) {
    const float3 p0 = f3(A.v[0], A.v[1], A.v[2]);
    const float3 p1 = f3(A.v[3], A.v[4], A.v[5]);
    const float3 p2 = f3(B.v[0], B.v[1], B.v[2]);
    const float3 p3 = f3(B.v[3], B.v[4], B.v[5]);

    const float3 d0 = sub3(p2, p0), d1 = sub3(p3, p0);
    const float3 d2 = sub3(p2, p1), d3 = sub3(p3, p1);

    const float3 u0 = cross3(d0, d1);
    const float3 u1 = cross3(d1, d3);
    const float3 u3 = cross3(d2, d0);

    const float n0 = dot3(u0, u0);
    const float n1 = dot3(u1, u1);
    const float n3 = dot3(u3, u3);

    const float d01 = dot3(u0, u1) * __builtin_amdgcn_rsqf(n0 * n1);
    const float d13 = dot3(u1, u3) * __builtin_amdgcn_rsqf(n1 * n3);
    const float d30 = dot3(u3, u0) * __builtin_amdgcn_rsqf(n3 * n0);

    const float omega = asin_fast(d01) + asin_fast(d13) + asin_fast(d30)
                      + 1.5707963267948966f;

    // sign( ((p3-p2) x (p1-p0)) . d0 ) == sign(-u0.d2); *sign == sign-bit XOR
    const float sv = -dot3(u0, d2);
    float r = omega * 0.15915494309189535f;
    const unsigned rb = __float_as_uint(r) ^ (__float_as_uint(sv) & 0x80000000u);
    return (sv == 0.0f) ? 0.0f : __uint_as_float(rb);
}

__global__ __launch_bounds__(256) void writhe_kernel(
    const float* __restrict__ xyz,
    float*       __restrict__ out,
    int S, int m /* = A-3 */)
{
    const int s = blockIdx.x * blockDim.x + threadIdx.x;
    if (s >= S) return;
    const int f0 = blockIdx.y * FPT;
    // blockIdx.z in [0, REP): identical work per slice (diagnostic only)

    // branchless s -> (i, j), exact fp32 FMA (all terms < 2^24)
    const float mf = (float)m;
    const float sf = (float)s;
    const float tm = 2.0f * mf + 1.0f;
    const float disc = fmaf(tm, tm, -8.0f * sf);
    int i = (int)(0.5f * (tm - __builtin_amdgcn_sqrtf(disc)));
    i = max(0, min(i, m - 1));
    #define RBF(ii) fmaf((float)(ii), mf, -0.5f * (float)(ii) * ((float)(ii) - 1.0f))
    i += (int)(i < m - 1 && RBF(i + 1) <= sf);
    i += (int)(i < m - 1 && RBF(i + 1) <= sf);
    i -= (int)(i > 0 && RBF(i) > sf);
    const int j = i + 2 + (int)(sf - RBF(i));
    #undef RBF

    const int oi = 3 * i, oj = 3 * j;
    const float* __restrict__ fx = xyz + (size_t)f0 * (ATOMS * 3);
    float* __restrict__ ob = out + (size_t)f0 * S + s;

    #pragma unroll
    for (int g = 0; g < FPT / G; ++g) {
        f6 A[G], B[G];
        float r[G];
        #pragma unroll
        for (int k = 0; k < G; ++k) {
            const float* p = fx + (size_t)(g * G + k) * (ATOMS * 3);
            A[k] = *reinterpret_cast<const f6*>(p + oi);
            B[k] = *reinterpret_cast<const f6*>(p + oj);
        }
        #pragma unroll
        for (int k = 0; k < G; ++k)
            r[k] = writhe_elem(A[k], B[k]);
        #pragma unroll
        for (int k = 0; k < G; ++k)
            ob[(size_t)(g * G + k) * S] = r[k];
    }
}

extern "C" void kernel_launch(void* const* d_in, const int* in_sizes, int n_in,
                              void* d_out, int out_size, void* d_ws, size_t ws_size,
                              hipStream_t stream)
{
    const float* xyz = (const float*)d_in[0];
    float*       out = (float*)d_out;

    const int F = in_sizes[0] / (ATOMS * 3);
    const int S = out_size / F;              // = (A-2)(A-3)/2
    const int m = (int)((-1.0 + sqrt(1.0 + 8.0 * (double)S)) * 0.5 + 0.5);

    dim3 grid((S + 255) / 256, F / FPT, REP);  // z = work replication (diag)
    writhe_kernel<<<grid, 256, 0, stream>>>(xyz, out, S, m);
}

// Round 17
// 22.159 us; speedup vs baseline: 2.1464x; 2.1464x over previous
//
#include <hip/hip_runtime.h>
#include <math.h>

#define ATOMS 200
#define FPT 4   // frames per thread = one ILP group of 4 independent chains.
                // R16 diagnostic: FPT=16 left only 4928 waves (54% occ cap);
                // FPT=4 gives 19.7k waves = 2.4x machine fill at VGPR<=64.

static __device__ __forceinline__ float3 f3(float x, float y, float z) {
    return make_float3(x, y, z);
}
static __device__ __forceinline__ float3 sub3(float3 a, float3 b) {
    return f3(a.x - b.x, a.y - b.y, a.z - b.z);
}
static __device__ __forceinline__ float dot3(float3 a, float3 b) {
    return fmaf(a.x, b.x, fmaf(a.y, b.y, a.z * b.z));
}
static __device__ __forceinline__ float3 cross3(float3 a, float3 b) {
    return f3(fmaf(a.y, b.z, -a.z * b.y),
              fmaf(a.z, b.x, -a.x * b.z),
              fmaf(a.x, b.y, -a.y * b.x));
}

// two consecutive atoms (24B) in one packed access
struct __attribute__((packed, aligned(4))) f6 { float v[6]; };

// asin via A&S 4.4.45: abs err <= 6.8e-5 rad (threshold is 2e-2)
static __device__ __forceinline__ float asin_fast(float x) {
    float a = fminf(fabsf(x), 1.0f);
    float t = __builtin_amdgcn_sqrtf(1.0f - a);
    float p = fmaf(a, -0.0187293f, 0.0742610f);
    p = fmaf(a, p, -0.2121144f);
    p = fmaf(a, p, 1.5707288f);
    return copysignf(fmaf(-t, p, 1.5707963267948966f), x);
}

static __device__ __forceinline__ float writhe_elem(const f6& A, const f6& B) {
    const float3 p0 = f3(A.v[0], A.v[1], A.v[2]);
    const float3 p1 = f3(A.v[3], A.v[4], A.v[5]);
    const float3 p2 = f3(B.v[0], B.v[1], B.v[2]);
    const float3 p3 = f3(B.v[3], B.v[4], B.v[5]);

    const float3 d0 = sub3(p2, p0), d1 = sub3(p3, p0);
    const float3 d2 = sub3(p2, p1), d3 = sub3(p3, p1);

    const float3 u0 = cross3(d0, d1);
    const float3 u1 = cross3(d1, d3);
    const float3 u3 = cross3(d2, d0);

    const float n0 = dot3(u0, u0);
    const float n1 = dot3(u1, u1);
    const float n3 = dot3(u3, u3);

    const float d01 = dot3(u0, u1) * __builtin_amdgcn_rsqf(n0 * n1);
    const float d13 = dot3(u1, u3) * __builtin_amdgcn_rsqf(n1 * n3);
    const float d30 = dot3(u3, u0) * __builtin_amdgcn_rsqf(n3 * n0);

    const float omega = asin_fast(d01) + asin_fast(d13) + asin_fast(d30)
                      + 1.5707963267948966f;

    // sign( ((p3-p2) x (p1-p0)) . d0 ) == sign(-u0.d2); *sign == sign-bit XOR
    const float sv = -dot3(u0, d2);
    float r = omega * 0.15915494309189535f;
    const unsigned rb = __float_as_uint(r) ^ (__float_as_uint(sv) & 0x80000000u);
    return (sv == 0.0f) ? 0.0f : __uint_as_float(rb);
}

__global__ __launch_bounds__(256) void writhe_kernel(
    const float* __restrict__ xyz,
    float*       __restrict__ out,
    int S, int m /* = A-3 */)
{
    const int s = blockIdx.x * blockDim.x + threadIdx.x;
    if (s >= S) return;
    const int f0 = blockIdx.y * FPT;

    // branchless s -> (i, j), exact fp32 FMA (all terms < 2^24)
    const float mf = (float)m;
    const float sf = (float)s;
    const float tm = 2.0f * mf + 1.0f;
    const float disc = fmaf(tm, tm, -8.0f * sf);
    int i = (int)(0.5f * (tm - __builtin_amdgcn_sqrtf(disc)));
    i = max(0, min(i, m - 1));
    #define RBF(ii) fmaf((float)(ii), mf, -0.5f * (float)(ii) * ((float)(ii) - 1.0f))
    i += (int)(i < m - 1 && RBF(i + 1) <= sf);
    i += (int)(i < m - 1 && RBF(i + 1) <= sf);
    i -= (int)(i > 0 && RBF(i) > sf);
    const int j = i + 2 + (int)(sf - RBF(i));
    #undef RBF

    const int oi = 3 * i, oj = 3 * j;
    const float* __restrict__ fx = xyz + (size_t)f0 * (ATOMS * 3);
    float* __restrict__ ob = out + (size_t)f0 * S + s;

    // 8 packed loads up front -> 4 independent math chains -> 4 stores
    f6 A[FPT], B[FPT];
    #pragma unroll
    for (int k = 0; k < FPT; ++k) {
        const float* p = fx + (size_t)k * (ATOMS * 3);
        A[k] = *reinterpret_cast<const f6*>(p + oi);
        B[k] = *reinterpret_cast<const f6*>(p + oj);
    }
    float r[FPT];
    #pragma unroll
    for (int k = 0; k < FPT; ++k)
        r[k] = writhe_elem(A[k], B[k]);
    #pragma unroll
    for (int k = 0; k < FPT; ++k)
        ob[(size_t)k * S] = r[k];
}

extern "C" void kernel_launch(void* const* d_in, const int* in_sizes, int n_in,
                              void* d_out, int out_size, void* d_ws, size_t ws_size,
                              hipStream_t stream)
{
    const float* xyz = (const float*)d_in[0];
    float*       out = (float*)d_out;

    const int F = in_sizes[0] / (ATOMS * 3);
    const int S = out_size / F;              // = (A-2)(A-3)/2
    const int m = (int)((-1.0 + sqrt(1.0 + 8.0 * (double)S)) * 0.5 + 0.5);

    dim3 grid((S + 255) / 256, (F + FPT - 1) / FPT);
    writhe_kernel<<<grid, 256, 0, stream>>>(xyz, out, S, m);
}

// Round 18
// 21.874 us; speedup vs baseline: 2.1744x; 1.0130x over previous
//
#include <hip/hip_runtime.h>
#include <math.h>

#define ATOMS 200
#define FPT 8   // frames per thread: 2 pipelined groups of 4.
                // R15/R16/R17 triplet: need BOTH >=8192 waves (fill) AND
                // long unrolled waves (pipeline + startup amortization).
                // FPT=8 -> 9750 waves (119% fill) x 2-group pipelining.
#define G   4   // frames per unrolled group (independent chains in flight)

static __device__ __forceinline__ float3 f3(float x, float y, float z) {
    return make_float3(x, y, z);
}
static __device__ __forceinline__ float3 sub3(float3 a, float3 b) {
    return f3(a.x - b.x, a.y - b.y, a.z - b.z);
}
static __device__ __forceinline__ float dot3(float3 a, float3 b) {
    return fmaf(a.x, b.x, fmaf(a.y, b.y, a.z * b.z));
}
static __device__ __forceinline__ float3 cross3(float3 a, float3 b) {
    return f3(fmaf(a.y, b.z, -a.z * b.y),
              fmaf(a.z, b.x, -a.x * b.z),
              fmaf(a.x, b.y, -a.y * b.x));
}

// two consecutive atoms (24B) in one packed access
struct __attribute__((packed, aligned(4))) f6 { float v[6]; };

// asin via A&S 4.4.45: abs err <= 6.8e-5 rad (threshold is 2e-2)
static __device__ __forceinline__ float asin_fast(float x) {
    float a = fminf(fabsf(x), 1.0f);
    float t = __builtin_amdgcn_sqrtf(1.0f - a);
    float p = fmaf(a, -0.0187293f, 0.0742610f);
    p = fmaf(a, p, -0.2121144f);
    p = fmaf(a, p, 1.5707288f);
    return copysignf(fmaf(-t, p, 1.5707963267948966f), x);
}

static __device__ __forceinline__ float writhe_elem(const f6& A, const f6& B) {
    const float3 p0 = f3(A.v[0], A.v[1], A.v[2]);
    const float3 p1 = f3(A.v[3], A.v[4], A.v[5]);
    const float3 p2 = f3(B.v[0], B.v[1], B.v[2]);
    const float3 p3 = f3(B.v[3], B.v[4], B.v[5]);

    const float3 d0 = sub3(p2, p0), d1 = sub3(p3, p0);
    const float3 d2 = sub3(p2, p1), d3 = sub3(p3, p1);

    const float3 u0 = cross3(d0, d1);
    const float3 u1 = cross3(d1, d3);
    const float3 u3 = cross3(d2, d0);

    const float n0 = dot3(u0, u0);
    const float n1 = dot3(u1, u1);
    const float n3 = dot3(u3, u3);

    const float d01 = dot3(u0, u1) * __builtin_amdgcn_rsqf(n0 * n1);
    const float d13 = dot3(u1, u3) * __builtin_amdgcn_rsqf(n1 * n3);
    const float d30 = dot3(u3, u0) * __builtin_amdgcn_rsqf(n3 * n0);

    const float omega = asin_fast(d01) + asin_fast(d13) + asin_fast(d30)
                      + 1.5707963267948966f;

    // sign( ((p3-p2) x (p1-p0)) . d0 ) == sign(-u0.d2); *sign == sign-bit XOR
    const float sv = -dot3(u0, d2);
    float r = omega * 0.15915494309189535f;
    const unsigned rb = __float_as_uint(r) ^ (__float_as_uint(sv) & 0x80000000u);
    return (sv == 0.0f) ? 0.0f : __uint_as_float(rb);
}

__global__ __launch_bounds__(256) void writhe_kernel(
    const float* __restrict__ xyz,
    float*       __restrict__ out,
    int S, int m /* = A-3 */)
{
    const int s = blockIdx.x * blockDim.x + threadIdx.x;
    if (s >= S) return;
    const int f0 = blockIdx.y * FPT;

    // branchless s -> (i, j), exact fp32 FMA (all terms < 2^24)
    const float mf = (float)m;
    const float sf = (float)s;
    const float tm = 2.0f * mf + 1.0f;
    const float disc = fmaf(tm, tm, -8.0f * sf);
    int i = (int)(0.5f * (tm - __builtin_amdgcn_sqrtf(disc)));
    i = max(0, min(i, m - 1));
    #define RBF(ii) fmaf((float)(ii), mf, -0.5f * (float)(ii) * ((float)(ii) - 1.0f))
    i += (int)(i < m - 1 && RBF(i + 1) <= sf);
    i += (int)(i < m - 1 && RBF(i + 1) <= sf);
    i -= (int)(i > 0 && RBF(i) > sf);
    const int j = i + 2 + (int)(sf - RBF(i));
    #undef RBF

    const int oi = 3 * i, oj = 3 * j;
    const float* __restrict__ fx = xyz + (size_t)f0 * (ATOMS * 3);
    float* __restrict__ ob = out + (size_t)f0 * S + s;

    #pragma unroll
    for (int g = 0; g < FPT / G; ++g) {
        f6 A[G], B[G];
        float r[G];
        #pragma unroll
        for (int k = 0; k < G; ++k) {
            const float* p = fx + (size_t)(g * G + k) * (ATOMS * 3);
            A[k] = *reinterpret_cast<const f6*>(p + oi);
            B[k] = *reinterpret_cast<const f6*>(p + oj);
        }
        #pragma unroll
        for (int k = 0; k < G; ++k)
            r[k] = writhe_elem(A[k], B[k]);
        #pragma unroll
        for (int k = 0; k < G; ++k)
            ob[(size_t)(g * G + k) * S] = r[k];
    }
}

extern "C" void kernel_launch(void* const* d_in, const int* in_sizes, int n_in,
                              void* d_out, int out_size, void* d_ws, size_t ws_size,
                              hipStream_t stream)
{
    const float* xyz = (const float*)d_in[0];
    float*       out = (float*)d_out;

    const int F = in_sizes[0] / (ATOMS * 3);
    const int S = out_size / F;              // = (A-2)(A-3)/2
    const int m = (int)((-1.0 + sqrt(1.0 + 8.0 * (double)S)) * 0.5 + 0.5);

    dim3 grid((S + 255) / 256, (F + FPT - 1) / FPT);
    writhe_kernel<<<grid, 256, 0, stream>>>(xyz, out, S, m);
}